// Round 3
// baseline (348.820 us; speedup 1.0000x reference)
//
#include <hip/hip_runtime.h>
#include <hip/hip_bf16.h>

typedef unsigned short u16;
typedef __attribute__((ext_vector_type(4))) float floatx4;
typedef __attribute__((ext_vector_type(8))) __bf16 bf16x8;

// ---------- helpers ----------
__device__ __forceinline__ u16 f2bf(float f) {
  unsigned int x = __builtin_bit_cast(unsigned int, f);
  unsigned int r = (x + 0x7fffu + ((x >> 16) & 1u)) >> 16;
  return (u16)r;
}
__device__ __forceinline__ float bf2f(u16 u) {
  unsigned int x = ((unsigned int)u) << 16;
  return __builtin_bit_cast(float, x);
}
__device__ __forceinline__ floatx4 mfma16(bf16x8 a, bf16x8 b, floatx4 c) {
  return __builtin_amdgcn_mfma_f32_16x16x32_bf16(a, b, c, 0, 0, 0);
}
__device__ __forceinline__ void gload16(const u16* g, u16* l) {
  __builtin_amdgcn_global_load_lds(
      (const __attribute__((address_space(1))) unsigned int*)g,
      (__attribute__((address_space(3))) unsigned int*)l, 16, 0, 0);
}
#define SCHEDB() __builtin_amdgcn_sched_barrier(0)
#define SBAR() __builtin_amdgcn_s_barrier()

// ---------- sizes ----------
#define BB 2
#define SS 2048
#define DM 2048
#define HH 16
#define PCOLS 6144   // qsem 1024 | ksem 1024 | qgeo 1024 | kgeo 1024 | v 2048

// ---------- prep kernels ----------
__global__ void convert_bf16_k(const float* __restrict__ src, u16* __restrict__ dst, size_t n) {
  size_t i = ((size_t)blockIdx.x * blockDim.x + threadIdx.x) * 4;
  if (i + 3 >= n) { for (size_t j = i; j < n; ++j) dst[j] = f2bf(src[j]); return; }
  float4 v = *(const float4*)&src[i];
  ushort4 o; o.x = f2bf(v.x); o.y = f2bf(v.y); o.z = f2bf(v.z); o.w = f2bf(v.w);
  *(ushort4*)&dst[i] = o;
}

// dst[c][r] = bf16(src[r][c]); dst row stride = rows (=K)
__global__ void transpose_w_k(const float* __restrict__ src, u16* __restrict__ dst,
                              int rows, int cols) {
  __shared__ float tile[32][33];
  int c0 = blockIdx.x * 32, r0 = blockIdx.y * 32;
  int tx = threadIdx.x, ty = threadIdx.y;
#pragma unroll
  for (int i = 0; i < 4; ++i)
    tile[ty + i * 8][tx] = src[(size_t)(r0 + ty + i * 8) * cols + c0 + tx];
  __syncthreads();
#pragma unroll
  for (int i = 0; i < 4; ++i)
    dst[(size_t)(c0 + ty + i * 8) * rows + r0 + tx] = f2bf(tile[tx][ty + i * 8]);
}

// V transpose: P cols [4096..6144) (bf16) -> VtG[(b*2048 + h*128+dv)][s]
__global__ void vtrans_k(const u16* __restrict__ P, u16* __restrict__ VtG) {
  __shared__ u16 t[32][33];
  int b = blockIdx.z;
  int c0 = blockIdx.x * 32;   // combined (h,dv) index
  int s0 = blockIdx.y * 32;
  int tx = threadIdx.x, ty = threadIdx.y;
#pragma unroll
  for (int i = 0; i < 4; ++i)
    t[ty + i * 8][tx] = P[((size_t)b * SS + s0 + ty + i * 8) * PCOLS + 4096 + c0 + tx];
  __syncthreads();
#pragma unroll
  for (int i = 0; i < 4; ++i)
    VtG[((size_t)b * 2048 + c0 + ty + i * 8) * SS + s0 + tx] = t[tx][ty + i * 8];
}

__global__ void rope_table_k(float* __restrict__ cosT, float* __restrict__ sinT) {
  int idx = blockIdx.x * 256 + threadIdx.x;       // 2048*32
  int s = idx >> 5, d = idx & 31;
  double inv = pow(10000.0, -(double)d / 32.0);
  double ang = (double)s * inv;
  cosT[idx] = (float)cos(ang);
  sinT[idx] = (float)sin(ang);
}

// in-place RoPE on P's qgeo (cols 2048..3071) and kgeo (cols 3072..4095)
__global__ void rope_apply_k(u16* __restrict__ P, const float* __restrict__ cosT,
                             const float* __restrict__ sinT) {
  int idx = blockIdx.x * 256 + threadIdx.x;       // rows(4096)*2*16*32
  int d = idx & 31, h = (idx >> 5) & 15, reg = (idx >> 9) & 1, row = idx >> 10;
  int s = row & (SS - 1);
  size_t base = (size_t)row * PCOLS + (reg ? 3072 : 2048) + h * 64 + d;
  float x1 = bf2f(P[base]), x2 = bf2f(P[base + 32]);
  float c = cosT[s * 32 + d], sn = sinT[s * 32 + d];
  P[base] = f2bf(x1 * c - x2 * sn);
  P[base + 32] = f2bf(x1 * sn + x2 * c);
}

// ---------- 8-phase GEMM: C(MxN) = A(MxK,bf16) * Bt(NxK,bf16)^T ----------
// BM=128, BN=256, BK=64, 512 threads (8 waves 2Mx4N), k-half LDS slabs,
// XOR swizzle g^=(row>>1)&3, counted vmcnt(4) at phases 4/8, setprio on MFMA.
// LDS u16 map: A[buf][kh] @ (buf*2+kh)*4096 (128x32); B[buf][kh] @ 16384+(buf*2+kh)*8192 (256x32).
template <bool OUTF32>
__global__ __launch_bounds__(512, 2)
void gemm8_k(const u16* __restrict__ A, const u16* __restrict__ Bt,
             void* __restrict__ Cout, int M, int N, int K) {
  __shared__ alignas(16) u16 lds[49152];   // 96 KiB
  const int tid = threadIdx.x;
  const int wid = tid >> 6, lane = tid & 63;
  const int lr = lane & 15, lg = lane >> 4;
  const int wr = wid >> 2, wc = wid & 3;
  const int m0 = blockIdx.y * 128, n0 = blockIdx.x * 256;
  const int NT = K >> 6;          // K-tiles of 64
  const int NT4 = NT * 4;         // slab count

  // read-side lane constants (row = 16*base + lr  =>  (row>>1)&3 == (lr>>1)&3)
  const int gA = ((lg ^ ((lr >> 1) & 3)) * 8);
  const int aoffL = lr * 32 + gA;

  // staging lane constants: thread i covers slab row i>>2, dest granule i&3,
  // logical granule = (i&3) ^ ((i>>3)&3)  (inverse-swizzled global source)
  const int srow = tid >> 2;                       // 0..127
  const int sgl = (((tid & 3) ^ ((tid >> 3) & 3)) * 8);
  const u16* Asrc = A + (size_t)(m0 + srow) * K + sgl;
  const u16* Bsrc0 = Bt + (size_t)(n0 + srow) * K + sgl;
  const u16* Bsrc1 = Bsrc0 + (size_t)128 * K;
  const int wbase = wid * 512;                     // per-wave LDS dest (u16)

  floatx4 acc[4][4];
#pragma unroll
  for (int m = 0; m < 4; ++m)
#pragma unroll
    for (int n = 0; n < 4; ++n) acc[m][n] = (floatx4){0.f, 0.f, 0.f, 0.f};

  auto stgA = [&](int tile, int kh) {
    gload16(Asrc + tile * 64 + kh * 32,
            lds + ((tile & 1) * 2 + kh) * 4096 + wbase);
  };
  auto stgB = [&](int tile, int kh) {
    u16* d = lds + 16384 + ((tile & 1) * 2 + kh) * 8192 + wbase;
    const u16* s0 = Bsrc0 + tile * 64 + kh * 32;
    const u16* s1 = Bsrc1 + tile * 64 + kh * 32;
    gload16(s0, d);
    gload16(s1, d + 4096);
  };
  // slab s: tile = s>>2, kind: 0=A-kh0(1 load), 1=B-kh0(2), 2=A-kh1(1), 3=B-kh1(2)
  auto stage_slab = [&](int s) {
    if (s >= NT4) return;
    int tile = s >> 2, kind = s & 3;
    if (kind == 0) stgA(tile, 0);
    else if (kind == 1) stgB(tile, 0);
    else if (kind == 2) stgA(tile, 1);
    else stgB(tile, 1);
  };

  // prologue: slabs 0..6 (tile0 complete + tile1 A0,B0,A1) = 10 loads
  for (int s = 0; s < 7; ++s) stage_slab(s);
  asm volatile("s_waitcnt vmcnt(4)" ::: "memory");   // tile0 landed; 4 loads in flight
  SCHEDB(); SBAR(); SCHEDB();

  bf16x8 af[4], bfv[2];

#pragma unroll 1
  for (int it = 0; it < (NT >> 1); ++it) {
    const int t = it * 2;
    const int sb = t * 4 + 6;
    const bool more = (t + 2 < NT);

#define PH(BUF, KK, NH, SL, DOVM)                                              \
    {                                                                          \
      const u16* Ab = lds + ((BUF) * 2 + (KK)) * 4096;                         \
      const u16* Bb = lds + 16384 + ((BUF) * 2 + (KK)) * 8192;                 \
      if ((NH) == 0) {                                                         \
        _Pragma("unroll") for (int m = 0; m < 4; ++m)                          \
          af[m] = *(const bf16x8*)&Ab[(wr * 64 + m * 16) * 32 + aoffL];        \
      }                                                                        \
      _Pragma("unroll") for (int j = 0; j < 2; ++j)                            \
        bfv[j] = *(const bf16x8*)&Bb[(wc * 64 + ((NH) * 2 + j) * 16) * 32 + aoffL]; \
      stage_slab(sb + (SL));                                                   \
      SCHEDB(); SBAR(); SCHEDB();                                              \
      __builtin_amdgcn_s_setprio(1);                                           \
      _Pragma("unroll") for (int m = 0; m < 4; ++m)                            \
        _Pragma("unroll") for (int j = 0; j < 2; ++j)                          \
          acc[m][(NH) * 2 + j] = mfma16(af[m], bfv[j], acc[m][(NH) * 2 + j]);  \
      __builtin_amdgcn_s_setprio(0);                                           \
      if (DOVM) {                                                              \
        if (more) asm volatile("s_waitcnt vmcnt(4)" ::: "memory");             \
        else      asm volatile("s_waitcnt vmcnt(0)" ::: "memory");             \
      }                                                                        \
      SCHEDB(); SBAR(); SCHEDB();                                              \
    }

    PH(0, 0, 0, 1, 0)
    PH(0, 0, 1, 2, 0)
    PH(0, 1, 0, 3, 0)
    PH(0, 1, 1, 4, 1)
    PH(1, 0, 0, 5, 0)
    PH(1, 0, 1, 6, 0)
    PH(1, 1, 0, 7, 0)
    PH(1, 1, 1, 8, 1)
#undef PH
  }

  // epilogue
#pragma unroll
  for (int m = 0; m < 4; ++m) {
    int row0 = m0 + wr * 64 + m * 16 + lg * 4;
#pragma unroll
    for (int n = 0; n < 4; ++n) {
      int col = n0 + wc * 64 + n * 16 + lr;
#pragma unroll
      for (int r = 0; r < 4; ++r) {
        size_t off = (size_t)(row0 + r) * N + col;
        if (OUTF32) ((float*)Cout)[off] = acc[m][n][r];
        else        ((u16*)Cout)[off] = f2bf(acc[m][n][r]);
      }
    }
  }
}

// ---------- flash attention with gated dual scores (QBLK=128, 8 waves, KVB=64) ----------
__device__ __forceinline__ bf16x8 load_scaled(const u16* p, float s) {
  uint4 raw = *(const uint4*)p;
  const u16* ru = (const u16*)&raw;
  bf16x8 out;
#pragma unroll
  for (int j = 0; j < 8; ++j) out[j] = (__bf16)(bf2f(ru[j]) * s);
  return out;
}

__global__ __launch_bounds__(512, 4)
void attn_k(const u16* __restrict__ P, const u16* __restrict__ VtG,
            const float* __restrict__ gate, u16* __restrict__ AttO) {
  // grid: x = 256 (16 rev-qblocks x 16 heads), y = B. Heavy q-blocks first.
  const int qbrev = blockIdx.x >> 4;
  const int h = blockIdx.x & 15;
  const int q0 = (15 - qbrev) * 128;
  const int b = blockIdx.y;
  const int tid = threadIdx.x, wid = tid >> 6, lane = tid & 63;
  const int lr = lane & 15, lg = lane >> 4;
  const size_t rowb = (size_t)b * SS;

  const float g = 1.f / (1.f + __expf(-gate[h]));
  const float ssc = g * 0.125f;          // g / sqrt(DS)
  const float gsc = (1.f - g) * 0.125f;  // (1-g) / sqrt(DG)

  __shared__ alignas(16) u16 Ks[64][72];
  __shared__ alignas(16) u16 Kg[64][72];
  __shared__ alignas(16) u16 Vt[128][72];
  __shared__ alignas(16) u16 Pw[8][16][72];

  // Q fragments (A-rows = q0 + wid*16 + lr), gate+scale folded in
  const u16* qbase = P + (rowb + q0 + wid * 16 + lr) * PCOLS + h * 64;
  bf16x8 qs[2], qg[2];
#pragma unroll
  for (int kk = 0; kk < 2; ++kk) {
    qs[kk] = load_scaled(qbase + kk * 32 + lg * 8, ssc);
    qg[kk] = load_scaled(qbase + 2048 + kk * 32 + lg * 8, gsc);
  }

  float m_r[4] = {-1e30f, -1e30f, -1e30f, -1e30f};
  float l_r[4] = {0.f, 0.f, 0.f, 0.f};
  floatx4 o[8];
#pragma unroll
  for (int n = 0; n < 8; ++n) o[n] = (floatx4){0.f, 0.f, 0.f, 0.f};

  const int srow = tid >> 3;           // 0..63
  const int sc8 = (tid & 7) * 8;       // 0..56

  const int nkv = q0 + 128;
  for (int kv0 = 0; kv0 < nkv; kv0 += 64) {
    __syncthreads();
    {  // stage K_sem, K_geo: 64 rows x 64 u16 (512 threads, one uint4 each)
      const u16* src = P + (rowb + kv0 + srow) * PCOLS;
      *(uint4*)&Ks[srow][sc8] = *(const uint4*)(src + 1024 + h * 64 + sc8);
      *(uint4*)&Kg[srow][sc8] = *(const uint4*)(src + 3072 + h * 64 + sc8);
    }
#pragma unroll
    for (int i = 0; i < 2; ++i) {  // stage V^T: 128 rows (dv) x 64 u16 (kv)
      int r = i * 64 + srow;
      *(uint4*)&Vt[r][sc8] =
          *(const uint4*)&VtG[((size_t)b * 2048 + h * 128 + r) * SS + kv0 + sc8];
    }
    __syncthreads();

    // QK^T: 4 kv-subtiles of 16
    floatx4 sc[4];
#pragma unroll
    for (int s = 0; s < 4; ++s) sc[s] = (floatx4){0.f, 0.f, 0.f, 0.f};
#pragma unroll
    for (int kk = 0; kk < 2; ++kk) {
#pragma unroll
      for (int s = 0; s < 4; ++s) {
        bf16x8 kf = *(const bf16x8*)&Ks[s * 16 + lr][kk * 32 + lg * 8];
        bf16x8 gf = *(const bf16x8*)&Kg[s * 16 + lr][kk * 32 + lg * 8];
        sc[s] = mfma16(qs[kk], kf, sc[s]);
        sc[s] = mfma16(qg[kk], gf, sc[s]);
      }
    }

    const bool needmask = (kv0 + 63 > q0 + wid * 16);
    float corr[4];
#pragma unroll
    for (int r = 0; r < 4; ++r) {
      int qr = q0 + wid * 16 + lg * 4 + r;
      float v0 = sc[0][r], v1 = sc[1][r], v2 = sc[2][r], v3 = sc[3][r];
      if (needmask) {
        v0 = (kv0 + lr      <= qr) ? v0 : -1e30f;
        v1 = (kv0 + 16 + lr <= qr) ? v1 : -1e30f;
        v2 = (kv0 + 32 + lr <= qr) ? v2 : -1e30f;
        v3 = (kv0 + 48 + lr <= qr) ? v3 : -1e30f;
      }
      float mx = fmaxf(fmaxf(v0, v1), fmaxf(v2, v3));
#pragma unroll
      for (int off = 8; off; off >>= 1) mx = fmaxf(mx, __shfl_xor(mx, off));
      float mnew = fmaxf(m_r[r], mx);
      corr[r] = __expf(m_r[r] - mnew);
      float p0 = __expf(v0 - mnew), p1 = __expf(v1 - mnew);
      float p2 = __expf(v2 - mnew), p3 = __expf(v3 - mnew);
      float ps = p0 + p1 + p2 + p3;
#pragma unroll
      for (int off = 8; off; off >>= 1) ps += __shfl_xor(ps, off);
      l_r[r] = l_r[r] * corr[r] + ps;
      m_r[r] = mnew;
      Pw[wid][lg * 4 + r][lr]      = f2bf(p0);
      Pw[wid][lg * 4 + r][16 + lr] = f2bf(p1);
      Pw[wid][lg * 4 + r][32 + lr] = f2bf(p2);
      Pw[wid][lg * 4 + r][48 + lr] = f2bf(p3);
    }
#pragma unroll
    for (int n = 0; n < 8; ++n)
#pragma unroll
      for (int r = 0; r < 4; ++r) o[n][r] *= corr[r];

    __asm__ volatile("s_waitcnt lgkmcnt(0)" ::: "memory");
    bf16x8 pa0 = *(const bf16x8*)&Pw[wid][lr][lg * 8];
    bf16x8 pa1 = *(const bf16x8*)&Pw[wid][lr][32 + lg * 8];
#pragma unroll
    for (int n = 0; n < 8; ++n) {
      bf16x8 vb0 = *(const bf16x8*)&Vt[n * 16 + lr][lg * 8];
      bf16x8 vb1 = *(const bf16x8*)&Vt[n * 16 + lr][32 + lg * 8];
      o[n] = mfma16(pa0, vb0, o[n]);
      o[n] = mfma16(pa1, vb1, o[n]);
    }
  }

#pragma unroll
  for (int n = 0; n < 8; ++n)
#pragma unroll
    for (int r = 0; r < 4; ++r) {
      float val = o[n][r] / l_r[r];
      AttO[(rowb + q0 + wid * 16 + lg * 4 + r) * (size_t)(HH * 128) + h * 128 + n * 16 + lr] =
          f2bf(val);
    }
}

// ---------- launch ----------
extern "C" void kernel_launch(void* const* d_in, const int* in_sizes, int n_in,
                              void* d_out, int out_size, void* d_ws, size_t ws_size,
                              hipStream_t stream) {
  const float* x       = (const float*)d_in[0];
  const float* wq_sem  = (const float*)d_in[1];
  const float* wk_sem  = (const float*)d_in[2];
  const float* wq_geo  = (const float*)d_in[3];
  const float* wk_geo  = (const float*)d_in[4];
  const float* wv      = (const float*)d_in[5];
  const float* wo      = (const float*)d_in[6];
  const float* gate    = (const float*)d_in[7];

  char* ws = (char*)d_ws;
  u16* Xbf   = (u16*)(ws);
  u16* WcatT = (u16*)(ws + 16777216);
  u16* WoT   = (u16*)(ws + 16777216 + 25165824);
  u16* P     = (u16*)(ws + 16777216 + 25165824 + 8388608);
  float* cosT = (float*)(ws + 16777216 + 25165824 + 8388608 + 50331648);
  float* sinT = cosT + 2048 * 32;
  u16* AttO = Xbf;    // Xbf dead after projection GEMM
  u16* VtG  = WcatT;  // WcatT dead after projection GEMM

  dim3 tb(32, 8);
  convert_bf16_k<<<8192, 256, 0, stream>>>(x, Xbf, (size_t)4096 * 2048);
  transpose_w_k<<<dim3(32, 64), tb, 0, stream>>>(wq_sem, WcatT + (size_t)0    * 2048, 2048, 1024);
  transpose_w_k<<<dim3(32, 64), tb, 0, stream>>>(wk_sem, WcatT + (size_t)1024 * 2048, 2048, 1024);
  transpose_w_k<<<dim3(32, 64), tb, 0, stream>>>(wq_geo, WcatT + (size_t)2048 * 2048, 2048, 1024);
  transpose_w_k<<<dim3(32, 64), tb, 0, stream>>>(wk_geo, WcatT + (size_t)3072 * 2048, 2048, 1024);
  transpose_w_k<<<dim3(64, 64), tb, 0, stream>>>(wv,     WcatT + (size_t)4096 * 2048, 2048, 2048);
  transpose_w_k<<<dim3(64, 64), tb, 0, stream>>>(wo,     WoT, 2048, 2048);
  rope_table_k<<<256, 256, 0, stream>>>(cosT, sinT);

  gemm8_k<false><<<dim3(24, 32), 512, 0, stream>>>(Xbf, WcatT, P, 4096, 6144, 2048);
  rope_apply_k<<<16384, 256, 0, stream>>>(P, cosT, sinT);
  vtrans_k<<<dim3(64, 64, 2), tb, 0, stream>>>(P, VtG);
  attn_k<<<dim3(256, 2), 512, 0, stream>>>(P, VtG, gate, AttO);
  gemm8_k<true><<<dim3(8, 32), 512, 0, stream>>>(AttO, WoT, d_out, 4096, 2048, 2048);
}

// Round 4
// 272.213 us; speedup vs baseline: 1.2814x; 1.2814x over previous
//
#include <hip/hip_runtime.h>
#include <hip/hip_bf16.h>

typedef unsigned short u16;
typedef __attribute__((ext_vector_type(4))) float floatx4;
typedef __attribute__((ext_vector_type(8))) __bf16 bf16x8;

// ---------- helpers ----------
__device__ __forceinline__ u16 f2bf(float f) {
  unsigned int x = __builtin_bit_cast(unsigned int, f);
  unsigned int r = (x + 0x7fffu + ((x >> 16) & 1u)) >> 16;
  return (u16)r;
}
__device__ __forceinline__ float bf2f(u16 u) {
  unsigned int x = ((unsigned int)u) << 16;
  return __builtin_bit_cast(float, x);
}
__device__ __forceinline__ floatx4 mfma16(bf16x8 a, bf16x8 b, floatx4 c) {
  return __builtin_amdgcn_mfma_f32_16x16x32_bf16(a, b, c, 0, 0, 0);
}
__device__ __forceinline__ void gload16(const u16* g, u16* l) {
  __builtin_amdgcn_global_load_lds(
      (const __attribute__((address_space(1))) unsigned int*)g,
      (__attribute__((address_space(3))) unsigned int*)l, 16, 0, 0);
}
#define SCHEDB() __builtin_amdgcn_sched_barrier(0)
#define SBAR() __builtin_amdgcn_s_barrier()

// ---------- sizes ----------
#define BB 2
#define SS 2048
#define DM 2048
#define HH 16
#define PCOLS 6144   // qsem 1024 | ksem 1024 | qgeo 1024 | kgeo 1024 | v 2048

// ---------- prep kernels ----------
__global__ void convert_bf16_k(const float* __restrict__ src, u16* __restrict__ dst, size_t n) {
  size_t i = ((size_t)blockIdx.x * blockDim.x + threadIdx.x) * 4;
  if (i + 3 >= n) { for (size_t j = i; j < n; ++j) dst[j] = f2bf(src[j]); return; }
  float4 v = *(const float4*)&src[i];
  ushort4 o; o.x = f2bf(v.x); o.y = f2bf(v.y); o.z = f2bf(v.z); o.w = f2bf(v.w);
  *(ushort4*)&dst[i] = o;
}

// all 6 weight transposes in one launch. dst[c][r] = bf16(src[r][c]), rows = 2048.
__global__ void transpose_all_k(const float* w0, const float* w1, const float* w2,
                                const float* w3, const float* w4, const float* w5,
                                u16* __restrict__ WcatT, u16* __restrict__ WoT) {
  __shared__ float tile[32][33];
  const int z = blockIdx.z;
  const float* src; u16* dst; int cols;
  if (z == 0)      { src = w0; dst = WcatT;                        cols = 1024; }
  else if (z == 1) { src = w1; dst = WcatT + (size_t)1024 * 2048;  cols = 1024; }
  else if (z == 2) { src = w2; dst = WcatT + (size_t)2048 * 2048;  cols = 1024; }
  else if (z == 3) { src = w3; dst = WcatT + (size_t)3072 * 2048;  cols = 1024; }
  else if (z == 4) { src = w4; dst = WcatT + (size_t)4096 * 2048;  cols = 2048; }
  else             { src = w5; dst = WoT;                          cols = 2048; }
  int c0 = blockIdx.x * 32;
  if (c0 >= cols) return;
  int r0 = blockIdx.y * 32;
  int tx = threadIdx.x, ty = threadIdx.y;
#pragma unroll
  for (int i = 0; i < 4; ++i)
    tile[ty + i * 8][tx] = src[(size_t)(r0 + ty + i * 8) * cols + c0 + tx];
  __syncthreads();
#pragma unroll
  for (int i = 0; i < 4; ++i)
    dst[(size_t)(c0 + ty + i * 8) * 2048 + r0 + tx] = f2bf(tile[tx][ty + i * 8]);
}

// V transpose: P cols [4096..6144) (bf16) -> VtG[(b*2048 + h*128+dv)][s]
__global__ void vtrans_k(const u16* __restrict__ P, u16* __restrict__ VtG) {
  __shared__ u16 t[32][33];
  int b = blockIdx.z;
  int c0 = blockIdx.x * 32;   // combined (h,dv) index
  int s0 = blockIdx.y * 32;
  int tx = threadIdx.x, ty = threadIdx.y;
#pragma unroll
  for (int i = 0; i < 4; ++i)
    t[ty + i * 8][tx] = P[((size_t)b * SS + s0 + ty + i * 8) * PCOLS + 4096 + c0 + tx];
  __syncthreads();
#pragma unroll
  for (int i = 0; i < 4; ++i)
    VtG[((size_t)b * 2048 + c0 + ty + i * 8) * SS + s0 + tx] = t[tx][ty + i * 8];
}

__global__ void rope_table_k(float* __restrict__ cosT, float* __restrict__ sinT) {
  int idx = blockIdx.x * 256 + threadIdx.x;       // 2048*32
  int s = idx >> 5, d = idx & 31;
  double inv = pow(10000.0, -(double)d / 32.0);
  double ang = (double)s * inv;
  cosT[idx] = (float)cos(ang);
  sinT[idx] = (float)sin(ang);
}

// in-place RoPE on P's qgeo (cols 2048..3071) and kgeo (cols 3072..4095)
__global__ void rope_apply_k(u16* __restrict__ P, const float* __restrict__ cosT,
                             const float* __restrict__ sinT) {
  int idx = blockIdx.x * 256 + threadIdx.x;       // rows(4096)*2*16*32
  int d = idx & 31, h = (idx >> 5) & 15, reg = (idx >> 9) & 1, row = idx >> 10;
  int s = row & (SS - 1);
  size_t base = (size_t)row * PCOLS + (reg ? 3072 : 2048) + h * 64 + d;
  float x1 = bf2f(P[base]), x2 = bf2f(P[base + 32]);
  float c = cosT[s * 32 + d], sn = sinT[s * 32 + d];
  P[base] = f2bf(x1 * c - x2 * sn);
  P[base + 32] = f2bf(x1 * sn + x2 * c);
}

// ---------- 8-phase GEMM: C(MxN) = A(MxK,bf16) * Bt(NxK,bf16)^T ----------
// BM=128, BN=256, BK=64, 512 threads (8 waves 2Mx4N), k-half LDS slabs,
// XOR swizzle g^=(row>>1)&3, counted vmcnt(4) at phases 4/8, setprio on MFMA.
template <bool OUTF32>
__global__ __launch_bounds__(512, 2)
void gemm8_k(const u16* __restrict__ A, const u16* __restrict__ Bt,
             void* __restrict__ Cout, int M, int N, int K) {
  __shared__ alignas(16) u16 lds[49152];   // 96 KiB
  const int tid = threadIdx.x;
  const int wid = tid >> 6, lane = tid & 63;
  const int lr = lane & 15, lg = lane >> 4;
  const int wr = wid >> 2, wc = wid & 3;
  const int m0 = blockIdx.y * 128, n0 = blockIdx.x * 256;
  const int NT = K >> 6;          // K-tiles of 64
  const int NT4 = NT * 4;         // slab count

  const int gA = ((lg ^ ((lr >> 1) & 3)) * 8);
  const int aoffL = lr * 32 + gA;

  const int srow = tid >> 2;                       // 0..127
  const int sgl = (((tid & 3) ^ ((tid >> 3) & 3)) * 8);
  const u16* Asrc = A + (size_t)(m0 + srow) * K + sgl;
  const u16* Bsrc0 = Bt + (size_t)(n0 + srow) * K + sgl;
  const u16* Bsrc1 = Bsrc0 + (size_t)128 * K;
  const int wbase = wid * 512;                     // per-wave LDS dest (u16)

  floatx4 acc[4][4];
#pragma unroll
  for (int m = 0; m < 4; ++m)
#pragma unroll
    for (int n = 0; n < 4; ++n) acc[m][n] = (floatx4){0.f, 0.f, 0.f, 0.f};

  auto stgA = [&](int tile, int kh) {
    gload16(Asrc + tile * 64 + kh * 32,
            lds + ((tile & 1) * 2 + kh) * 4096 + wbase);
  };
  auto stgB = [&](int tile, int kh) {
    u16* d = lds + 16384 + ((tile & 1) * 2 + kh) * 8192 + wbase;
    const u16* s0 = Bsrc0 + tile * 64 + kh * 32;
    const u16* s1 = Bsrc1 + tile * 64 + kh * 32;
    gload16(s0, d);
    gload16(s1, d + 4096);
  };
  auto stage_slab = [&](int s) {
    if (s >= NT4) return;
    int tile = s >> 2, kind = s & 3;
    if (kind == 0) stgA(tile, 0);
    else if (kind == 1) stgB(tile, 0);
    else if (kind == 2) stgA(tile, 1);
    else stgB(tile, 1);
  };

  for (int s = 0; s < 7; ++s) stage_slab(s);
  asm volatile("s_waitcnt vmcnt(4)" ::: "memory");
  SCHEDB(); SBAR(); SCHEDB();

  bf16x8 af[4], bfv[2];

#pragma unroll 1
  for (int it = 0; it < (NT >> 1); ++it) {
    const int t = it * 2;
    const int sb = t * 4 + 6;
    const bool more = (t + 2 < NT);

#define PH(BUF, KK, NH, SL, DOVM)                                              \
    {                                                                          \
      const u16* Ab = lds + ((BUF) * 2 + (KK)) * 4096;                         \
      const u16* Bb = lds + 16384 + ((BUF) * 2 + (KK)) * 8192;                 \
      if ((NH) == 0) {                                                         \
        _Pragma("unroll") for (int m = 0; m < 4; ++m)                          \
          af[m] = *(const bf16x8*)&Ab[(wr * 64 + m * 16) * 32 + aoffL];        \
      }                                                                        \
      _Pragma("unroll") for (int j = 0; j < 2; ++j)                            \
        bfv[j] = *(const bf16x8*)&Bb[(wc * 64 + ((NH) * 2 + j) * 16) * 32 + aoffL]; \
      stage_slab(sb + (SL));                                                   \
      SCHEDB(); SBAR(); SCHEDB();                                              \
      __builtin_amdgcn_s_setprio(1);                                           \
      _Pragma("unroll") for (int m = 0; m < 4; ++m)                            \
        _Pragma("unroll") for (int j = 0; j < 2; ++j)                          \
          acc[m][(NH) * 2 + j] = mfma16(af[m], bfv[j], acc[m][(NH) * 2 + j]);  \
      __builtin_amdgcn_s_setprio(0);                                           \
      if (DOVM) {                                                              \
        if (more) asm volatile("s_waitcnt vmcnt(4)" ::: "memory");             \
        else      asm volatile("s_waitcnt vmcnt(0)" ::: "memory");             \
      }                                                                        \
      SCHEDB(); SBAR(); SCHEDB();                                              \
    }

    PH(0, 0, 0, 1, 0)
    PH(0, 0, 1, 2, 0)
    PH(0, 1, 0, 3, 0)
    PH(0, 1, 1, 4, 1)
    PH(1, 0, 0, 5, 0)
    PH(1, 0, 1, 6, 0)
    PH(1, 1, 0, 7, 0)
    PH(1, 1, 1, 8, 1)
#undef PH
  }

#pragma unroll
  for (int m = 0; m < 4; ++m) {
    int row0 = m0 + wr * 64 + m * 16 + lg * 4;
#pragma unroll
    for (int n = 0; n < 4; ++n) {
      int col = n0 + wc * 64 + n * 16 + lr;
#pragma unroll
      for (int r = 0; r < 4; ++r) {
        size_t off = (size_t)(row0 + r) * N + col;
        if (OUTF32) ((float*)Cout)[off] = acc[m][n][r];
        else        ((u16*)Cout)[off] = f2bf(acc[m][n][r]);
      }
    }
  }
}

// ---------- flash attention: swapped QK^T, per-lane softmax, pair-balanced ----------
__device__ __forceinline__ bf16x8 load_scaled(const u16* p, float s) {
  uint4 raw = *(const uint4*)p;
  const u16* ru = (const u16*)&raw;
  bf16x8 out;
#pragma unroll
  for (int j = 0; j < 8; ++j) out[j] = (__bf16)(bf2f(ru[j]) * s);
  return out;
}

__global__ __launch_bounds__(256, 3)
void attn_k(const u16* __restrict__ P, const u16* __restrict__ VtG,
            const float* __restrict__ gate, u16* __restrict__ AttO) {
  // grid: x = 256 (pair 0..15 x 16 heads), y = B. Block does q-tiles pairi and 31-pairi
  // (64 rows each): (pairi+1) + (32-pairi) = 33 kv-iterations per block — perfect balance.
  const int pairi = blockIdx.x >> 4;
  const int h = blockIdx.x & 15;
  const int b = blockIdx.y;
  const int tid = threadIdx.x, wid = tid >> 6, lane = tid & 63;
  const int lr = lane & 15, lg = lane >> 4;
  const size_t rowb = (size_t)b * SS;

  const float g = 1.f / (1.f + __expf(-gate[h]));
  const float ssc = g * 0.125f;          // g / sqrt(DS)
  const float gsc = (1.f - g) * 0.125f;  // (1-g) / sqrt(DG)

  // all tiles [rows][64] linear, granule-swizzled: byte ^= (row&7)<<4
  __shared__ alignas(16) u16 Ks[64 * 64];
  __shared__ alignas(16) u16 Kg[64 * 64];
  __shared__ alignas(16) u16 Vt[128 * 64];
  __shared__ alignas(16) u16 Pw[4][16 * 64];

  // staging constants: thread covers granule-slot tid (+256,...): row tid>>3, dst granule tid&7,
  // source granule = (tid&7) ^ (row&7)  (inverse swizzle on global source)
  const int strow = tid >> 3;                 // 0..31
  const int stg = ((tid & 7) ^ (strow & 7)) * 8;
  const int swz = lr & 7;                     // read-side swizzle (row&7 == lr&7)

  for (int half = 0; half < 2; ++half) {
    const int qb = half ? (31 - pairi) : pairi;
    const int q0 = qb * 64;

    // Q fragments (B-operand: lane holds Q[q = q0+wid*16+lr][k = kk*32+lg*8..+7])
    const u16* qbase = P + (rowb + q0 + wid * 16 + lr) * PCOLS + h * 64;
    bf16x8 qs[2], qg[2];
#pragma unroll
    for (int kk = 0; kk < 2; ++kk) {
      qs[kk] = load_scaled(qbase + kk * 32 + lg * 8, ssc);
      qg[kk] = load_scaled(qbase + 2048 + kk * 32 + lg * 8, gsc);
    }

    float m_r = -1e30f, l_r = 0.f;
    floatx4 o[8];
#pragma unroll
    for (int n = 0; n < 8; ++n) o[n] = (floatx4){0.f, 0.f, 0.f, 0.f};

    const int nkv = q0 + 64;
    for (int kv0 = 0; kv0 < nkv; kv0 += 64) {
      __syncthreads();
      {  // stage K_sem/K_geo rows 0..63 via global_load_lds (linear dest, pre-swizzled src)
        const u16* ks = P + (rowb + kv0 + strow) * PCOLS + 1024 + h * 64 + stg;
        const u16* gs = P + (rowb + kv0 + strow) * PCOLS + 3072 + h * 64 + stg;
        gload16(ks, Ks + wid * 512);
        gload16(gs, Kg + wid * 512);
        gload16(ks + (size_t)32 * PCOLS, Ks + 2048 + wid * 512);
        gload16(gs + (size_t)32 * PCOLS, Kg + 2048 + wid * 512);
      }
      {  // stage V^T rows (dv) 0..127
        const u16* vs = VtG + ((size_t)b * 2048 + h * 128 + strow) * SS + kv0 + stg;
#pragma unroll
        for (int c = 0; c < 4; ++c)
          gload16(vs + (size_t)(c * 32) * SS, Vt + c * 2048 + wid * 512);
      }
      __syncthreads();   // compiler drains vmcnt before barrier

      // swapped QK^T: sc[s] = S^T tile; lane holds score(q=q0+wid*16+lr, k=kv0+s*16+lg*4+r)
      floatx4 sc[4];
#pragma unroll
      for (int s = 0; s < 4; ++s) sc[s] = (floatx4){0.f, 0.f, 0.f, 0.f};
#pragma unroll
      for (int kk = 0; kk < 2; ++kk) {
#pragma unroll
        for (int s = 0; s < 4; ++s) {
          bf16x8 kf = *(const bf16x8*)&Ks[(s * 16 + lr) * 64 + ((kk * 4 + lg) ^ swz) * 8];
          bf16x8 gf = *(const bf16x8*)&Kg[(s * 16 + lr) * 64 + ((kk * 4 + lg) ^ swz) * 8];
          sc[s] = mfma16(kf, qs[kk], sc[s]);
          sc[s] = mfma16(gf, qg[kk], sc[s]);
        }
      }

      // per-lane softmax over this lane's 16 values (its q-row = lr)
      const int qrow = q0 + wid * 16 + lr;
      const bool needmask = (kv0 + 63 > q0 + wid * 16);
      float vv[4][4];
      float vmax = -1e30f;
#pragma unroll
      for (int s = 0; s < 4; ++s)
#pragma unroll
        for (int r = 0; r < 4; ++r) {
          float val = sc[s][r];
          if (needmask) val = (kv0 + s * 16 + lg * 4 + r <= qrow) ? val : -1e30f;
          vv[s][r] = val;
          vmax = fmaxf(vmax, val);
        }
      vmax = fmaxf(vmax, __shfl_xor(vmax, 16));
      vmax = fmaxf(vmax, __shfl_xor(vmax, 32));
      float mnew = fmaxf(m_r, vmax);
      float corr = __expf(m_r - mnew);
      float psum = 0.f;
#pragma unroll
      for (int s = 0; s < 4; ++s)
#pragma unroll
        for (int r = 0; r < 4; ++r) {
          vv[s][r] = __expf(vv[s][r] - mnew);
          psum += vv[s][r];
        }
      psum += __shfl_xor(psum, 16);
      psum += __shfl_xor(psum, 32);
      l_r = l_r * corr + psum;
      m_r = mnew;

      // pack P to bf16 pairs, write swizzled: value k=s*16+lg*4+2t(,+1) at row lr
#pragma unroll
      for (int s = 0; s < 4; ++s)
#pragma unroll
        for (int t = 0; t < 2; ++t) {
          unsigned int w;
          asm("v_cvt_pk_bf16_f32 %0, %1, %2" : "=v"(w) : "v"(vv[s][2 * t]), "v"(vv[s][2 * t + 1]));
          // granule gu = s*2 + (lg>>1); within-granule u16 off = (lg&1)*4 + t*2
          int u16off = lr * 64 + ((s * 2 + (lg >> 1)) ^ swz) * 8 + (lg & 1) * 4 + t * 2;
          *(unsigned int*)&Pw[wid][u16off] = w;
        }

      // redistribute corr to o-rows (o[n][r] is q-row lg*4+r): lanes 0..15 hold row=lane's corr
      float crr[4];
#pragma unroll
      for (int r = 0; r < 4; ++r) crr[r] = __shfl(corr, lg * 4 + r);
#pragma unroll
      for (int n = 0; n < 8; ++n)
#pragma unroll
        for (int r = 0; r < 4; ++r) o[n][r] *= crr[r];

      asm volatile("s_waitcnt lgkmcnt(0)" ::: "memory");
      SCHEDB();
      // PV: A = P[q=lr][k-chunk], B = Vt[dv=n*16+lr][k-chunk]
      bf16x8 pa0 = *(const bf16x8*)&Pw[wid][lr * 64 + (lg ^ swz) * 8];
      bf16x8 pa1 = *(const bf16x8*)&Pw[wid][lr * 64 + ((4 + lg) ^ swz) * 8];
#pragma unroll
      for (int n = 0; n < 8; ++n) {
        bf16x8 vb0 = *(const bf16x8*)&Vt[(n * 16 + lr) * 64 + (lg ^ swz) * 8];
        bf16x8 vb1 = *(const bf16x8*)&Vt[(n * 16 + lr) * 64 + ((4 + lg) ^ swz) * 8];
        o[n] = mfma16(pa0, vb0, o[n]);
        o[n] = mfma16(pa1, vb1, o[n]);
      }
    }

    float linv = 1.f / l_r;
    float lnv[4];
#pragma unroll
    for (int r = 0; r < 4; ++r) lnv[r] = __shfl(linv, lg * 4 + r);
#pragma unroll
    for (int n = 0; n < 8; ++n)
#pragma unroll
      for (int r = 0; r < 4; ++r) {
        float val = o[n][r] * lnv[r];
        AttO[(rowb + q0 + wid * 16 + lg * 4 + r) * (size_t)(HH * 128) + h * 128 + n * 16 + lr] =
            f2bf(val);
      }
  }
}

// ---------- launch ----------
extern "C" void kernel_launch(void* const* d_in, const int* in_sizes, int n_in,
                              void* d_out, int out_size, void* d_ws, size_t ws_size,
                              hipStream_t stream) {
  const float* x       = (const float*)d_in[0];
  const float* wq_sem  = (const float*)d_in[1];
  const float* wk_sem  = (const float*)d_in[2];
  const float* wq_geo  = (const float*)d_in[3];
  const float* wk_geo  = (const float*)d_in[4];
  const float* wv      = (const float*)d_in[5];
  const float* wo      = (const float*)d_in[6];
  const float* gate    = (const float*)d_in[7];

  char* ws = (char*)d_ws;
  u16* Xbf   = (u16*)(ws);
  u16* WcatT = (u16*)(ws + 16777216);
  u16* WoT   = (u16*)(ws + 16777216 + 25165824);
  u16* P     = (u16*)(ws + 16777216 + 25165824 + 8388608);
  float* cosT = (float*)(ws + 16777216 + 25165824 + 8388608 + 50331648);
  float* sinT = cosT + 2048 * 32;
  u16* AttO = Xbf;    // Xbf dead after projection GEMM
  u16* VtG  = WcatT;  // WcatT dead after projection GEMM

  dim3 tb(32, 8);
  convert_bf16_k<<<8192, 256, 0, stream>>>(x, Xbf, (size_t)4096 * 2048);
  transpose_all_k<<<dim3(64, 64, 6), tb, 0, stream>>>(wq_sem, wk_sem, wq_geo, wk_geo,
                                                      wv, wo, WcatT, WoT);
  rope_table_k<<<256, 256, 0, stream>>>(cosT, sinT);

  gemm8_k<false><<<dim3(24, 32), 512, 0, stream>>>(Xbf, WcatT, P, 4096, 6144, 2048);
  rope_apply_k<<<16384, 256, 0, stream>>>(P, cosT, sinT);
  vtrans_k<<<dim3(64, 64, 2), tb, 0, stream>>>(P, VtG);
  attn_k<<<dim3(256, 2), 256, 0, stream>>>(P, VtG, gate, AttO);
  gemm8_k<true><<<dim3(8, 32), 512, 0, stream>>>(AttO, WoT, d_out, 4096, 2048, 2048);
}

// Round 5
// 265.970 us; speedup vs baseline: 1.3115x; 1.0235x over previous
//
#include <hip/hip_runtime.h>
#include <hip/hip_bf16.h>

typedef unsigned short u16;
typedef __attribute__((ext_vector_type(4))) float floatx4;
typedef __attribute__((ext_vector_type(8))) __bf16 bf16x8;

// ---------- helpers ----------
__device__ __forceinline__ u16 f2bf(float f) {
  unsigned int x = __builtin_bit_cast(unsigned int, f);
  unsigned int r = (x + 0x7fffu + ((x >> 16) & 1u)) >> 16;
  return (u16)r;
}
__device__ __forceinline__ float bf2f(u16 u) {
  unsigned int x = ((unsigned int)u) << 16;
  return __builtin_bit_cast(float, x);
}
__device__ __forceinline__ floatx4 mfma16(bf16x8 a, bf16x8 b, floatx4 c) {
  return __builtin_amdgcn_mfma_f32_16x16x32_bf16(a, b, c, 0, 0, 0);
}
__device__ __forceinline__ void gload16(const u16* g, u16* l) {
  __builtin_amdgcn_global_load_lds(
      (const __attribute__((address_space(1))) unsigned int*)g,
      (__attribute__((address_space(3))) unsigned int*)l, 16, 0, 0);
}
#define SCHEDB() __builtin_amdgcn_sched_barrier(0)
#define SBAR() __builtin_amdgcn_s_barrier()

// ---------- sizes ----------
#define BB 2
#define SS 2048
#define DM 2048
#define HH 16
#define PCOLS 6144   // qsem 1024 | ksem 1024 | qgeo 1024 | kgeo 1024 | v 2048

// ---------- prep kernels ----------
__global__ void convert_bf16_k(const float* __restrict__ src, u16* __restrict__ dst, size_t n) {
  size_t i = ((size_t)blockIdx.x * blockDim.x + threadIdx.x) * 4;
  if (i + 3 >= n) { for (size_t j = i; j < n; ++j) dst[j] = f2bf(src[j]); return; }
  float4 v = *(const float4*)&src[i];
  ushort4 o; o.x = f2bf(v.x); o.y = f2bf(v.y); o.z = f2bf(v.z); o.w = f2bf(v.w);
  *(ushort4*)&dst[i] = o;
}

// all 6 weight transposes in one launch. dst[c][r] = bf16(src[r][c]), rows = 2048.
__global__ void transpose_all_k(const float* w0, const float* w1, const float* w2,
                                const float* w3, const float* w4, const float* w5,
                                u16* __restrict__ WcatT, u16* __restrict__ WoT) {
  __shared__ float tile[32][33];
  const int z = blockIdx.z;
  const float* src; u16* dst; int cols;
  if (z == 0)      { src = w0; dst = WcatT;                        cols = 1024; }
  else if (z == 1) { src = w1; dst = WcatT + (size_t)1024 * 2048;  cols = 1024; }
  else if (z == 2) { src = w2; dst = WcatT + (size_t)2048 * 2048;  cols = 1024; }
  else if (z == 3) { src = w3; dst = WcatT + (size_t)3072 * 2048;  cols = 1024; }
  else if (z == 4) { src = w4; dst = WcatT + (size_t)4096 * 2048;  cols = 2048; }
  else             { src = w5; dst = WoT;                          cols = 2048; }
  int c0 = blockIdx.x * 32;
  if (c0 >= cols) return;
  int r0 = blockIdx.y * 32;
  int tx = threadIdx.x, ty = threadIdx.y;
#pragma unroll
  for (int i = 0; i < 4; ++i)
    tile[ty + i * 8][tx] = src[(size_t)(r0 + ty + i * 8) * cols + c0 + tx];
  __syncthreads();
#pragma unroll
  for (int i = 0; i < 4; ++i)
    dst[(size_t)(c0 + ty + i * 8) * 2048 + r0 + tx] = f2bf(tile[tx][ty + i * 8]);
}

// V transpose: P cols [4096..6144) (bf16) -> VtG[(b*2048 + h*128+dv)][s]
__global__ void vtrans_k(const u16* __restrict__ P, u16* __restrict__ VtG) {
  __shared__ u16 t[32][33];
  int b = blockIdx.z;
  int c0 = blockIdx.x * 32;   // combined (h,dv) index
  int s0 = blockIdx.y * 32;
  int tx = threadIdx.x, ty = threadIdx.y;
#pragma unroll
  for (int i = 0; i < 4; ++i)
    t[ty + i * 8][tx] = P[((size_t)b * SS + s0 + ty + i * 8) * PCOLS + 4096 + c0 + tx];
  __syncthreads();
#pragma unroll
  for (int i = 0; i < 4; ++i)
    VtG[((size_t)b * 2048 + c0 + ty + i * 8) * SS + s0 + tx] = t[tx][ty + i * 8];
}

__global__ void rope_table_k(float* __restrict__ cosT, float* __restrict__ sinT) {
  int idx = blockIdx.x * 256 + threadIdx.x;       // 2048*32
  int s = idx >> 5, d = idx & 31;
  double inv = pow(10000.0, -(double)d / 32.0);
  double ang = (double)s * inv;
  cosT[idx] = (float)cos(ang);
  sinT[idx] = (float)sin(ang);
}

// in-place RoPE on P's qgeo (cols 2048..3071) and kgeo (cols 3072..4095)
__global__ void rope_apply_k(u16* __restrict__ P, const float* __restrict__ cosT,
                             const float* __restrict__ sinT) {
  int idx = blockIdx.x * 256 + threadIdx.x;       // rows(4096)*2*16*32
  int d = idx & 31, h = (idx >> 5) & 15, reg = (idx >> 9) & 1, row = idx >> 10;
  int s = row & (SS - 1);
  size_t base = (size_t)row * PCOLS + (reg ? 3072 : 2048) + h * 64 + d;
  float x1 = bf2f(P[base]), x2 = bf2f(P[base + 32]);
  float c = cosT[s * 32 + d], sn = sinT[s * 32 + d];
  P[base] = f2bf(x1 * c - x2 * sn);
  P[base + 32] = f2bf(x1 * sn + x2 * c);
}

// ---------- 8-phase GEMM, 4 waves, big per-wave tile ----------
// C(MxN) = A(MxK,bf16) * Bt(NxK,bf16)^T.  BM=128, BN=NFB*64, BK=64.
// 4 waves (1/SIMD), per-wave output 128 x (NFB*16).  K-half LDS slabs,
// XOR swizzle granule ^= (row>>1)&3, counted vmcnt, setprio on MFMA.
// LDS u16 map: A[buf][kh] @ (buf*2+kh)*4096 (128x32);
//              B[buf][kh] @ 16384 + (buf*2+kh)*NFB*2048 (NFB*64 x 32).
template <int NFB, bool OUTF32>
__global__ __launch_bounds__(256, 1)
void gemm4_k(const u16* __restrict__ A, const u16* __restrict__ Bt,
             void* __restrict__ Cout, int M, int N, int K) {
  constexpr int BH = NFB / 2;              // bfv frags per phase
  __shared__ alignas(16) u16 lds[16384 + NFB * 8192];
  const int tid = threadIdx.x;
  const int wid = tid >> 6, lane = tid & 63;
  const int lr = lane & 15, lg = lane >> 4;
  const int m0 = blockIdx.y * 128, n0 = blockIdx.x * (NFB * 64);
  const int NT = K >> 6;                   // K-tiles of 64
  const int NSLAB = NT * 4;

  // read-side offset: row*32 + swizzled granule (row&... (row>>1)&3 == (lr>>1)&3)
  const int aoff = lr * 32 + ((lg ^ ((lr >> 1) & 3)) * 8);

  // staging: per call a wave covers 16 rows x 32 u16; row = call*64 + wid*16 + (lane>>2),
  // dest granule lane&3, source granule (lane&3)^((row>>1)&3) = (lane&3)^((lane>>3)&3)
  const int srow = wid * 16 + (lane >> 2);
  const int sgl = (((lane & 3) ^ ((lane >> 3) & 3)) * 8);
  const u16* Asrc = A + (size_t)(m0 + srow) * K + sgl;
  const u16* Bsrc = Bt + (size_t)(n0 + srow) * K + sgl;

  floatx4 acc[8][NFB];
#pragma unroll
  for (int m = 0; m < 8; ++m)
#pragma unroll
    for (int n = 0; n < NFB; ++n) acc[m][n] = (floatx4){0.f, 0.f, 0.f, 0.f};

  auto stgA = [&](int tile, int kh) {
    u16* d = lds + ((tile & 1) * 2 + kh) * 4096 + wid * 512;
    const u16* s = Asrc + tile * 64 + kh * 32;
#pragma unroll
    for (int c = 0; c < 2; ++c) gload16(s + (size_t)(c * 64) * K, d + c * 2048);
  };
  auto stgB = [&](int tile, int kh) {
    u16* d = lds + 16384 + ((tile & 1) * 2 + kh) * (NFB * 2048) + wid * 512;
    const u16* s = Bsrc + tile * 64 + kh * 32;
#pragma unroll
    for (int c = 0; c < NFB; ++c) gload16(s + (size_t)(c * 64) * K, d + c * 2048);
  };
  // slab s: tile = s>>2; kind 0=A-kh0, 1=B-kh0, 2=A-kh1, 3=B-kh1
  auto stage_slab = [&](int s) {
    if (s >= NSLAB) return;
    int tile = s >> 2, kind = s & 3;
    if (kind == 0) stgA(tile, 0);
    else if (kind == 1) stgB(tile, 0);
    else if (kind == 2) stgA(tile, 1);
    else stgB(tile, 1);
  };

  // prologue: tile0 complete + tile1 {A0,B0,A1}; leaves 4+NFB loads in flight
  for (int s = 0; s < 7; ++s) stage_slab(s);
  if constexpr (NFB == 6) asm volatile("s_waitcnt vmcnt(10)" ::: "memory");
  else                    asm volatile("s_waitcnt vmcnt(8)" ::: "memory");
  SCHEDB(); SBAR(); SCHEDB();

  bf16x8 af[8], bfv[BH];

#pragma unroll 1
  for (int it = 0; it < (NT >> 1); ++it) {
    const int t = it * 2;
    const int sb = t * 4 + 6;
    const bool more = (t + 2 < NT);

#define PH(BUF, KK, NH, SL, DOVM)                                               \
    {                                                                           \
      const u16* Ab = lds + ((BUF) * 2 + (KK)) * 4096;                          \
      const u16* Bb = lds + 16384 + ((BUF) * 2 + (KK)) * (NFB * 2048);          \
      if ((NH) == 0) {                                                          \
        _Pragma("unroll") for (int m = 0; m < 8; ++m)                           \
          af[m] = *(const bf16x8*)&Ab[(m * 16) * 32 + aoff];                    \
      }                                                                         \
      _Pragma("unroll") for (int j = 0; j < BH; ++j)                            \
        bfv[j] = *(const bf16x8*)&Bb[(wid * NFB * 16 + ((NH) * BH + j) * 16) * 32 + aoff]; \
      stage_slab(sb + (SL));                                                    \
      SCHEDB(); SBAR(); SCHEDB();                                               \
      __builtin_amdgcn_s_setprio(1);                                            \
      _Pragma("unroll") for (int m = 0; m < 8; ++m)                             \
        _Pragma("unroll") for (int j = 0; j < BH; ++j)                          \
          acc[m][(NH) * BH + j] = mfma16(af[m], bfv[j], acc[m][(NH) * BH + j]); \
      __builtin_amdgcn_s_setprio(0);                                            \
      if (DOVM) {                                                               \
        if (more) {                                                             \
          if constexpr (NFB == 6) asm volatile("s_waitcnt vmcnt(10)" ::: "memory"); \
          else                    asm volatile("s_waitcnt vmcnt(8)" ::: "memory");  \
        } else {                                                                \
          asm volatile("s_waitcnt vmcnt(0)" ::: "memory");                      \
        }                                                                       \
      }                                                                         \
      SCHEDB(); SBAR(); SCHEDB();                                               \
    }

    PH(0, 0, 0, 1, 0)
    PH(0, 0, 1, 2, 0)
    PH(0, 1, 0, 3, 0)
    PH(0, 1, 1, 4, 1)
    PH(1, 0, 0, 5, 0)
    PH(1, 0, 1, 6, 0)
    PH(1, 1, 0, 7, 0)
    PH(1, 1, 1, 8, 1)
#undef PH
  }

  // epilogue
#pragma unroll
  for (int m = 0; m < 8; ++m) {
    int row0 = m0 + m * 16 + lg * 4;
#pragma unroll
    for (int n = 0; n < NFB; ++n) {
      int col = n0 + wid * NFB * 16 + n * 16 + lr;
#pragma unroll
      for (int r = 0; r < 4; ++r) {
        size_t off = (size_t)(row0 + r) * N + col;
        if (OUTF32) ((float*)Cout)[off] = acc[m][n][r];
        else        ((u16*)Cout)[off] = f2bf(acc[m][n][r]);
      }
    }
  }
}

// ---------- flash attention: swapped QK^T, per-lane softmax, pair-balanced ----------
__device__ __forceinline__ bf16x8 load_scaled(const u16* p, float s) {
  uint4 raw = *(const uint4*)p;
  const u16* ru = (const u16*)&raw;
  bf16x8 out;
#pragma unroll
  for (int j = 0; j < 8; ++j) out[j] = (__bf16)(bf2f(ru[j]) * s);
  return out;
}

__global__ __launch_bounds__(256, 3)
void attn_k(const u16* __restrict__ P, const u16* __restrict__ VtG,
            const float* __restrict__ gate, u16* __restrict__ AttO) {
  // grid: x = 256 (pair 0..15 x 16 heads), y = B. Block does q-tiles pairi and 31-pairi
  // (64 rows each): (pairi+1) + (32-pairi) = 33 kv-iterations per block — perfect balance.
  const int pairi = blockIdx.x >> 4;
  const int h = blockIdx.x & 15;
  const int b = blockIdx.y;
  const int tid = threadIdx.x, wid = tid >> 6, lane = tid & 63;
  const int lr = lane & 15, lg = lane >> 4;
  const size_t rowb = (size_t)b * SS;

  const float g = 1.f / (1.f + __expf(-gate[h]));
  const float ssc = g * 0.125f;          // g / sqrt(DS)
  const float gsc = (1.f - g) * 0.125f;  // (1-g) / sqrt(DG)

  // all tiles [rows][64] linear, granule-swizzled: byte ^= (row&7)<<4
  __shared__ alignas(16) u16 Ks[64 * 64];
  __shared__ alignas(16) u16 Kg[64 * 64];
  __shared__ alignas(16) u16 Vt[128 * 64];
  __shared__ alignas(16) u16 Pw[4][16 * 64];

  const int strow = tid >> 3;                 // 0..31
  const int stg = ((tid & 7) ^ (strow & 7)) * 8;
  const int swz = lr & 7;                     // read-side swizzle (row&7 == lr&7)

  for (int half = 0; half < 2; ++half) {
    const int qb = half ? (31 - pairi) : pairi;
    const int q0 = qb * 64;

    // Q fragments (B-operand: lane holds Q[q = q0+wid*16+lr][k = kk*32+lg*8..+7])
    const u16* qbase = P + (rowb + q0 + wid * 16 + lr) * PCOLS + h * 64;
    bf16x8 qs[2], qg[2];
#pragma unroll
    for (int kk = 0; kk < 2; ++kk) {
      qs[kk] = load_scaled(qbase + kk * 32 + lg * 8, ssc);
      qg[kk] = load_scaled(qbase + 2048 + kk * 32 + lg * 8, gsc);
    }

    float m_r = -1e30f, l_r = 0.f;
    floatx4 o[8];
#pragma unroll
    for (int n = 0; n < 8; ++n) o[n] = (floatx4){0.f, 0.f, 0.f, 0.f};

    const int nkv = q0 + 64;
    for (int kv0 = 0; kv0 < nkv; kv0 += 64) {
      __syncthreads();
      {  // stage K_sem/K_geo rows 0..63 via global_load_lds (linear dest, pre-swizzled src)
        const u16* ks = P + (rowb + kv0 + strow) * PCOLS + 1024 + h * 64 + stg;
        const u16* gs = P + (rowb + kv0 + strow) * PCOLS + 3072 + h * 64 + stg;
        gload16(ks, Ks + wid * 512);
        gload16(gs, Kg + wid * 512);
        gload16(ks + (size_t)32 * PCOLS, Ks + 2048 + wid * 512);
        gload16(gs + (size_t)32 * PCOLS, Kg + 2048 + wid * 512);
      }
      {  // stage V^T rows (dv) 0..127
        const u16* vs = VtG + ((size_t)b * 2048 + h * 128 + strow) * SS + kv0 + stg;
#pragma unroll
        for (int c = 0; c < 4; ++c)
          gload16(vs + (size_t)(c * 32) * SS, Vt + c * 2048 + wid * 512);
      }
      __syncthreads();   // compiler drains vmcnt before barrier

      // swapped QK^T: lane holds score(q=q0+wid*16+lr, k=kv0+s*16+lg*4+r)
      floatx4 sc[4];
#pragma unroll
      for (int s = 0; s < 4; ++s) sc[s] = (floatx4){0.f, 0.f, 0.f, 0.f};
#pragma unroll
      for (int kk = 0; kk < 2; ++kk) {
#pragma unroll
        for (int s = 0; s < 4; ++s) {
          bf16x8 kf = *(const bf16x8*)&Ks[(s * 16 + lr) * 64 + ((kk * 4 + lg) ^ swz) * 8];
          bf16x8 gf = *(const bf16x8*)&Kg[(s * 16 + lr) * 64 + ((kk * 4 + lg) ^ swz) * 8];
          sc[s] = mfma16(kf, qs[kk], sc[s]);
          sc[s] = mfma16(gf, qg[kk], sc[s]);
        }
      }

      // per-lane softmax over this lane's 16 values (its q-row = lr)
      const int qrow = q0 + wid * 16 + lr;
      const bool needmask = (kv0 + 63 > q0 + wid * 16);
      float vv[4][4];
      float vmax = -1e30f;
#pragma unroll
      for (int s = 0; s < 4; ++s)
#pragma unroll
        for (int r = 0; r < 4; ++r) {
          float val = sc[s][r];
          if (needmask) val = (kv0 + s * 16 + lg * 4 + r <= qrow) ? val : -1e30f;
          vv[s][r] = val;
          vmax = fmaxf(vmax, val);
        }
      vmax = fmaxf(vmax, __shfl_xor(vmax, 16));
      vmax = fmaxf(vmax, __shfl_xor(vmax, 32));
      float mnew = fmaxf(m_r, vmax);
      float corr = __expf(m_r - mnew);
      float psum = 0.f;
#pragma unroll
      for (int s = 0; s < 4; ++s)
#pragma unroll
        for (int r = 0; r < 4; ++r) {
          vv[s][r] = __expf(vv[s][r] - mnew);
          psum += vv[s][r];
        }
      psum += __shfl_xor(psum, 16);
      psum += __shfl_xor(psum, 32);
      l_r = l_r * corr + psum;
      m_r = mnew;

      // pack P to bf16 pairs, write swizzled: value k=s*16+lg*4+2t(,+1) at row lr
#pragma unroll
      for (int s = 0; s < 4; ++s)
#pragma unroll
        for (int t = 0; t < 2; ++t) {
          unsigned int w;
          asm("v_cvt_pk_bf16_f32 %0, %1, %2" : "=v"(w) : "v"(vv[s][2 * t]), "v"(vv[s][2 * t + 1]));
          int u16off = lr * 64 + ((s * 2 + (lg >> 1)) ^ swz) * 8 + (lg & 1) * 4 + t * 2;
          *(unsigned int*)&Pw[wid][u16off] = w;
        }

      // redistribute corr to o-rows (o[n][r] is q-row lg*4+r)
      float crr[4];
#pragma unroll
      for (int r = 0; r < 4; ++r) crr[r] = __shfl(corr, lg * 4 + r);
#pragma unroll
      for (int n = 0; n < 8; ++n)
#pragma unroll
        for (int r = 0; r < 4; ++r) o[n][r] *= crr[r];

      asm volatile("s_waitcnt lgkmcnt(0)" ::: "memory");
      SCHEDB();
      // PV: A = P[q=lr][k-chunk], B = Vt[dv=n*16+lr][k-chunk]
      bf16x8 pa0 = *(const bf16x8*)&Pw[wid][lr * 64 + (lg ^ swz) * 8];
      bf16x8 pa1 = *(const bf16x8*)&Pw[wid][lr * 64 + ((4 + lg) ^ swz) * 8];
#pragma unroll
      for (int n = 0; n < 8; ++n) {
        bf16x8 vb0 = *(const bf16x8*)&Vt[(n * 16 + lr) * 64 + (lg ^ swz) * 8];
        bf16x8 vb1 = *(const bf16x8*)&Vt[(n * 16 + lr) * 64 + ((4 + lg) ^ swz) * 8];
        o[n] = mfma16(pa0, vb0, o[n]);
        o[n] = mfma16(pa1, vb1, o[n]);
      }
    }

    float linv = 1.f / l_r;
    float lnv[4];
#pragma unroll
    for (int r = 0; r < 4; ++r) lnv[r] = __shfl(linv, lg * 4 + r);
#pragma unroll
    for (int n = 0; n < 8; ++n)
#pragma unroll
      for (int r = 0; r < 4; ++r) {
        float val = o[n][r] * lnv[r];
        AttO[(rowb + q0 + wid * 16 + lg * 4 + r) * (size_t)(HH * 128) + h * 128 + n * 16 + lr] =
            f2bf(val);
      }
  }
}

// ---------- launch ----------
extern "C" void kernel_launch(void* const* d_in, const int* in_sizes, int n_in,
                              void* d_out, int out_size, void* d_ws, size_t ws_size,
                              hipStream_t stream) {
  const float* x       = (const float*)d_in[0];
  const float* wq_sem  = (const float*)d_in[1];
  const float* wk_sem  = (const float*)d_in[2];
  const float* wq_geo  = (const float*)d_in[3];
  const float* wk_geo  = (const float*)d_in[4];
  const float* wv      = (const float*)d_in[5];
  const float* wo      = (const float*)d_in[6];
  const float* gate    = (const float*)d_in[7];

  char* ws = (char*)d_ws;
  u16* Xbf   = (u16*)(ws);
  u16* WcatT = (u16*)(ws + 16777216);
  u16* WoT   = (u16*)(ws + 16777216 + 25165824);
  u16* P     = (u16*)(ws + 16777216 + 25165824 + 8388608);
  float* cosT = (float*)(ws + 16777216 + 25165824 + 8388608 + 50331648);
  float* sinT = cosT + 2048 * 32;
  u16* AttO = Xbf;    // Xbf dead after projection GEMM
  u16* VtG  = WcatT;  // WcatT dead after projection GEMM

  dim3 tb(32, 8);
  convert_bf16_k<<<8192, 256, 0, stream>>>(x, Xbf, (size_t)4096 * 2048);
  transpose_all_k<<<dim3(64, 64, 6), tb, 0, stream>>>(wq_sem, wk_sem, wq_geo, wk_geo,
                                                      wv, wo, WcatT, WoT);
  rope_table_k<<<256, 256, 0, stream>>>(cosT, sinT);

  // proj: BN=384 -> grid 16x32 = 512 blocks = 2 balanced rounds at 1 block/CU
  gemm4_k<6, false><<<dim3(16, 32), 256, 0, stream>>>(Xbf, WcatT, P, 4096, 6144, 2048);
  rope_apply_k<<<16384, 256, 0, stream>>>(P, cosT, sinT);
  vtrans_k<<<dim3(64, 64, 2), tb, 0, stream>>>(P, VtG);
  attn_k<<<dim3(256, 2), 256, 0, stream>>>(P, VtG, gate, AttO);
  // wo: BN=256 -> grid 8x32 = 256 blocks = 1 balanced round
  gemm4_k<4, true><<<dim3(8, 32), 256, 0, stream>>>(AttO, WoT, d_out, 4096, 2048, 2048);
}